// Round 13
// baseline (281.310 us; speedup 1.0000x reference)
//
#include <hip/hip_runtime.h>
#include <hip/hip_bf16.h>

typedef __bf16 bf16x8 __attribute__((ext_vector_type(8)));
typedef float f32x4 __attribute__((ext_vector_type(4)));
typedef float f32x16 __attribute__((ext_vector_type(16)));
typedef unsigned u32x4 __attribute__((ext_vector_type(4)));

#define MFMA16(a,b,c) __builtin_amdgcn_mfma_f32_16x16x32_bf16((a),(b),(c),0,0,0)
#define MFMA32(a,b,c) __builtin_amdgcn_mfma_f32_32x32x16_bf16((a),(b),(c),0,0,0)

__device__ __forceinline__ float bf2f(const __hip_bfloat16 h){ return __bfloat162float(h); }
__device__ __forceinline__ __hip_bfloat16 f2bf(float f){ return __float2bfloat16(f); }
__device__ __forceinline__ __bf16 f2raw(float f){
  return __builtin_bit_cast(__bf16, __builtin_bit_cast(unsigned short, __float2bfloat16(f)));
}

__device__ __forceinline__ unsigned pk2(float a, float b){
  unsigned lo = __builtin_bit_cast(unsigned short, __float2bfloat16(a));
  unsigned hi = __builtin_bit_cast(unsigned short, __float2bfloat16(b));
  return lo | (hi << 16);
}
__device__ __forceinline__ void pl32swap(unsigned &x, unsigned &y){
  asm volatile("v_permlane32_swap_b32 %0, %1" : "+v"(x), "+v"(y));
}
// async global->LDS, 16B per lane; lds dest = uniform base + lane*16
__device__ __forceinline__ void gload16(const void* g, void* l){
  __builtin_amdgcn_global_load_lds((const __attribute__((address_space(1))) unsigned int*)g,
                                   (__attribute__((address_space(3))) unsigned int*)l, 16, 0, 0);
}

// fragment-pack index for qpk/kpk (B-frag, 32-row tiles)
__device__ __forceinline__ size_t pk_idx(int grp, int ntile, int t, int d){
  int t32 = t >> 5, ql = t & 31, i = d >> 4, kh = (d >> 3) & 1, j = d & 7;
  return ((size_t)(grp*ntile + t32)*8 + i)*512 + (kh*32 + ql)*8 + j;
}
// fragment-pack index for qep/kep (16x16 B-frag, 16-row tiles)
__device__ __forceinline__ size_t ep_idx(int grp, int t, int d){
  int t16 = t >> 4, lr = t & 15, f = d >> 5, lg = (d >> 3) & 3, j = d & 7;
  return (((size_t)grp*128 + t16)*4 + f)*512 + (lg*16 + lr)*8 + j;
}

// ---------------- rope cos/sin table ----------------
__global__ void k_rope_table(float* __restrict__ ct, float* __restrict__ st){
  int e = blockIdx.x*256 + threadIdx.x;
  if (e >= 2048*64) return;
  int t = e >> 6, d = e & 63;
  float inv = expf(-(float)d * 0.14391156831212787f);
  float ang = (float)t * inv;
  ct[e] = cosf(ang);
  st[e] = sinf(ang);
}

// ---------------- f32 -> bf16 elementwise ----------------
__global__ void k_cvt_bf16(const float* __restrict__ in, __hip_bfloat16* __restrict__ out, int n4){
  int i = blockIdx.x*256 + threadIdx.x;
  if (i >= n4) return;
  float4 v = reinterpret_cast<const float4*>(in)[i];
  ushort4 o;
  o.x = __builtin_bit_cast(unsigned short, f2bf(v.x));
  o.y = __builtin_bit_cast(unsigned short, f2bf(v.y));
  o.z = __builtin_bit_cast(unsigned short, f2bf(v.z));
  o.w = __builtin_bit_cast(unsigned short, f2bf(v.w));
  reinterpret_cast<ushort4*>(out)[i] = o;
}

// ---------------- fused weight transposes: Wq,Wk,Wv -> WqkvT; Wo -> WoT ----------------
__global__ __launch_bounds__(256) void k_transpose_w(const float* __restrict__ Wq,
                                                     const float* __restrict__ Wk,
                                                     const float* __restrict__ Wv,
                                                     const float* __restrict__ Wo,
                                                     __hip_bfloat16* __restrict__ WqkvT,
                                                     __hip_bfloat16* __restrict__ WoT){
  __shared__ float tile[64][65];
  int id = blockIdx.x;
  const float* in; __hip_bfloat16* out; int C, bx, by;
  if (id < 1024)      { in=Wq; out=WqkvT;                         C=2048; bx=id&31;          by=id>>5; }
  else if (id < 1280) { int i=id-1024; in=Wk; out=WqkvT+(size_t)2048*2048; C=512; bx=i&7;    by=i>>3; }
  else if (id < 1536) { int i=id-1280; in=Wv; out=WqkvT+(size_t)2560*2048; C=512; bx=i&7;    by=i>>3; }
  else                { int i=id-1536; in=Wo; out=WoT;            C=2048; bx=i&31;           by=i>>5; }
  const int R = 2048;
  int ct_ = bx*64, rt = by*64;
  int tx = threadIdx.x & 63, ty = threadIdx.x >> 6;
  #pragma unroll
  for (int i=0;i<16;++i){ int lr = i*4 + ty; tile[lr][tx] = in[(size_t)(rt+lr)*C + ct_+tx]; }
  __syncthreads();
  #pragma unroll
  for (int i=0;i<16;++i){ int lr = i*4 + ty; out[(size_t)(ct_+lr)*R + rt+tx] = f2bf(tile[tx][lr]); }
}

// ---------------- GEMM: 128x64 tile, 2-wave blocks, XCD-swizzled 1D grid ----------------
__global__ __launch_bounds__(128) void k_gemm_lds2(const __hip_bfloat16* __restrict__ A,
                                                   const __hip_bfloat16* __restrict__ BT,
                                                   float* __restrict__ C, int M, int N, int K){
  __shared__ __hip_bfloat16 As[128*64];   // 16KB
  __shared__ __hip_bfloat16 Bs[64*64];    // 8KB
  int nwg = gridDim.x;
  int cpx = nwg >> 3;
  int wg  = blockIdx.x;
  int swz = (wg & 7)*cpx + (wg >> 3);     // bijective XCD swizzle
  int nbx = N >> 6;
  int bn = (swz % nbx)*64, bm = (swz / nbx)*128;
  int tid = threadIdx.x, w = tid >> 6, l = tid & 63, lr = l & 15, lg = l >> 4;
  int wr = w*64;
  int srow = tid >> 3;
  int scol = (tid & 7)*8;
  f32x4 z = {0.f,0.f,0.f,0.f};
  f32x4 acc[4][4];
  #pragma unroll
  for (int i=0;i<4;++i){
    #pragma unroll
    for (int j=0;j<4;++j) acc[i][j] = z;
  }
  for (int bk=0; bk<K; bk+=64){
    #pragma unroll
    for (int i=0;i<8;++i)
      gload16(&A[(size_t)(bm + i*16 + srow)*K + bk + scol], &As[i*1024 + tid*8]);
    #pragma unroll
    for (int i=0;i<4;++i)
      gload16(&BT[(size_t)(bn + i*16 + srow)*K + bk + scol], &Bs[i*1024 + tid*8]);
    __syncthreads();
    __builtin_amdgcn_s_setprio(1);
    #pragma unroll
    for (int kk=0; kk<2; ++kk){
      bf16x8 af[4], bfr[4];
      #pragma unroll
      for (int mi=0;mi<4;++mi) af[mi]  = *reinterpret_cast<const bf16x8*>(&As[(wr+mi*16+lr)*64 + kk*32 + lg*8]);
      #pragma unroll
      for (int ni=0;ni<4;++ni) bfr[ni] = *reinterpret_cast<const bf16x8*>(&Bs[(ni*16+lr)*64 + kk*32 + lg*8]);
      #pragma unroll
      for (int mi=0;mi<4;++mi){
        #pragma unroll
        for (int ni=0;ni<4;++ni)
          acc[mi][ni] = MFMA16(af[mi], bfr[ni], acc[mi][ni]);
      }
    }
    __builtin_amdgcn_s_setprio(0);
    __syncthreads();
  }
  #pragma unroll
  for (int mi=0;mi<4;++mi){
    #pragma unroll
    for (int ni=0;ni<4;++ni){
      #pragma unroll
      for (int r=0;r<4;++r)
        C[(size_t)(bm+wr+mi*16+lg*4+r)*N + (bn+ni*16+lr)] = acc[mi][ni][r];
    }
  }
}

// ---------------- gate cumsum (log2 domain): bt_all[t][kv][k], eC = 2^bC ----------------
__global__ __launch_bounds__(128) void k_gates(const float* __restrict__ qkv,
                                               float* __restrict__ bt_all,
                                               float* __restrict__ eC){
  int c = blockIdx.x, kv = blockIdx.y, k = threadIdx.x;
  float b = 0.f;
  #pragma unroll 8
  for (int t=0;t<64;++t){
    float x = qkv[(size_t)(c*64+t)*3072 + 2048 + kv*128 + k];
    float gl = (fminf(x,0.f) - log1pf(expf(-fabsf(x)))) * 0.09016844005f; // logsigmoid/16 * log2e
    b += gl;
    bt_all[(size_t)(c*64+t)*512 + kv*128 + k] = b;
  }
  eC[((size_t)kv*32 + c)*128 + k] = exp2f(b);
}

// ---------------- fused q+k postproc: softmax + rope + gate-scale ----------------
__global__ __launch_bounds__(256) void k_qkpost(const float* __restrict__ qkv, const float* __restrict__ ct,
                                                const float* __restrict__ st, const float* __restrict__ bt_all,
                                                __hip_bfloat16* __restrict__ qpk, __hip_bfloat16* __restrict__ qep,
                                                __hip_bfloat16* __restrict__ kpk, __hip_bfloat16* __restrict__ ke,
                                                __hip_bfloat16* __restrict__ kep){
  int bid = blockIdx.x;
  int i = threadIdx.x & 63;
  if (bid < 8192){
    int g = bid*4 + (threadIdx.x >> 6);
    int t = g >> 4, h = g & 15;
    size_t base = (size_t)t*3072 + h*128;
    float a = qkv[base + i], b = qkv[base + 64 + i];
    float mx = fmaxf(a,b);
    #pragma unroll
    for (int off=1; off<64; off<<=1) mx = fmaxf(mx, __shfl_xor(mx, off));
    float ea = expf(a-mx), eb = expf(b-mx);
    float sm = ea+eb;
    #pragma unroll
    for (int off=1; off<64; off<<=1) sm += __shfl_xor(sm, off);
    float r = 1.0f/sm;
    const float* bp = &bt_all[(size_t)t*512 + (h>>2)*128];
    qep[ep_idx(h, t, i)]    = f2bf(exp2f(bp[i])    * (ea*r));
    qep[ep_idx(h, t, 64+i)] = f2bf(exp2f(bp[64+i]) * (eb*r));
    const float scale = 0.12751745f; // (1/sqrt(128)) * log2(e)
    float co = ct[t*64+i], si = st[t*64+i];
    qpk[pk_idx(h, 64, t, i)]    = f2bf((a*co - b*si)*scale);
    qpk[pk_idx(h, 64, t, 64+i)] = f2bf((b*co + a*si)*scale);
  } else {
    int g = (bid-8192)*4 + (threadIdx.x >> 6);
    int t = g >> 2, kv = g & 3;
    size_t base = (size_t)t*3072 + 2048 + kv*128;
    float a = qkv[base + i], b = qkv[base + 64 + i];
    float mx = fmaxf(a,b);
    #pragma unroll
    for (int off=1; off<64; off<<=1) mx = fmaxf(mx, __shfl_xor(mx, off));
    float ea = expf(a-mx), eb = expf(b-mx);
    float sm = ea+eb;
    #pragma unroll
    for (int off=1; off<64; off<<=1) sm += __shfl_xor(sm, off);
    float r = 1.0f/sm;
    const float* bp = &bt_all[(size_t)t*512 + kv*128];
    float kea = exp2f(-bp[i])    * (ea*r);
    float keb = exp2f(-bp[64+i]) * (eb*r);
    size_t ob = ((size_t)t*4 + kv)*128;
    ke[ob+i]    = f2bf(kea);
    ke[ob+64+i] = f2bf(keb);
    kep[ep_idx(kv, t, i)]    = f2bf(kea);
    kep[ep_idx(kv, t, 64+i)] = f2bf(keb);
    float co = ct[t*64+i], si = st[t*64+i];
    kpk[pk_idx(kv, 64, t, i)]    = f2bf(a*co - b*si);
    kpk[pk_idx(kv, 64, t, 64+i)] = f2bf(b*co + a*si);
  }
}

// ---------------- fused V prep: qkv -> vt + vpk + vpk16 (one LDS pass) ----------------
__global__ __launch_bounds__(256) void k_vprep(const float* __restrict__ qkv,
                                               __hip_bfloat16* __restrict__ vt,
                                               __hip_bfloat16* __restrict__ vpk,
                                               __hip_bfloat16* __restrict__ vpk16){
  __shared__ float lds[64*132];
  int s = blockIdx.x, kv = blockIdx.y;
  int tid = threadIdx.x;
  #pragma unroll
  for (int it=0; it<8; ++it){
    int i = it*256 + tid;          // 0..2047 float4s
    int t = i >> 5, dc = (i & 31)*4;
    float4 v = *reinterpret_cast<const float4*>(&qkv[(size_t)(s*64+t)*3072 + 2560 + kv*128 + dc]);
    *reinterpret_cast<float4*>(&lds[t*132 + dc]) = v;
  }
  __syncthreads();
  // vt[(kv*128+d)*2048 + s*64 + tg..+7]
  #pragma unroll
  for (int it=0; it<4; ++it){
    int i = it*256 + tid;          // 0..1023
    int d = i >> 3, tg = (i & 7)*8;
    bf16x8 o;
    #pragma unroll
    for (int j=0;j<8;++j) o[j] = f2raw(lds[(tg+j)*132 + d]);
    *reinterpret_cast<bf16x8*>(&vt[((size_t)kv*128 + d)*2048 + s*64 + tg]) = o;
  }
  // vpk: A-frag for 32x32 PV
  #pragma unroll
  for (int it=0; it<4; ++it){
    int j2 = it*256 + tid;
    int dt = j2 >> 8, kq = (j2 >> 6) & 3, l = j2 & 63;
    int ts = kq*16 + (l>>5)*8, ds = dt*32 + (l&31);
    bf16x8 o;
    #pragma unroll
    for (int j=0;j<8;++j) o[j] = f2raw(lds[(ts+j)*132 + ds]);
    *reinterpret_cast<bf16x8*>(&vpk[((((size_t)kv*32 + s)*4 + dt)*4 + kq)*512 + l*8]) = o;
  }
  // vpk16: A-frag for 16x16 PV (gla_out)
  #pragma unroll
  for (int it=0; it<4; ++it){
    int j3 = it*256 + tid;
    int oc = j3 >> 7, f2 = (j3 >> 6) & 1, l = j3 & 63;
    int ts = f2*32 + (l>>4)*8, ds = oc*16 + (l&15);
    bf16x8 o;
    #pragma unroll
    for (int j=0;j<8;++j) o[j] = f2raw(lds[(ts+j)*132 + ds]);
    *reinterpret_cast<bf16x8*>(&vpk16[((((size_t)kv*32 + s)*8 + oc)*2 + f2)*512 + l*8]) = o;
  }
}

// ---------------- per-chunk KV: ckv[kd][vd] = ke^T(128x64) @ v(64x128) ----------------
__global__ __launch_bounds__(256) void k_ckv(const __hip_bfloat16* __restrict__ ke,
                                             const __hip_bfloat16* __restrict__ vt,
                                             float* __restrict__ ckv){
  __shared__ __hip_bfloat16 kt[128*72];
  int c = blockIdx.x, kv = blockIdx.y;
  int tid = threadIdx.x, w = tid>>6, l = tid&63, lr=l&15, lg=l>>4;
  int wr = (w>>1)*64, wc = (w&1)*64;
  #pragma unroll
  for (int r=0;r<4;++r){
    int idx = r*256 + tid;
    int t  = idx >> 4;
    int k0 = (idx & 15)*8;
    bf16x8 v = *reinterpret_cast<const bf16x8*>(&ke[((size_t)(c*64+t)*4 + kv)*128 + k0]);
    #pragma unroll
    for (int j=0;j<8;++j) kt[(k0+j)*72 + t] = __builtin_bit_cast(__hip_bfloat16, (unsigned short)__builtin_bit_cast(unsigned short, v[j]));
  }
  __syncthreads();
  f32x4 z = {0.f,0.f,0.f,0.f};
  f32x4 acc[4][4];
  #pragma unroll
  for (int i=0;i<4;++i){
    #pragma unroll
    for (int j=0;j<4;++j) acc[i][j]=z;
  }
  size_t sb = (size_t)kv*32 + c;
  #pragma unroll
  for (int kf2=0;kf2<2;++kf2){
    bf16x8 af[4], bfr[4];
    #pragma unroll
    for (int mi=0;mi<4;++mi)
      af[mi] = *reinterpret_cast<const bf16x8*>(&kt[(wr+mi*16+lr)*72 + kf2*32 + lg*8]);
    #pragma unroll
    for (int ni=0;ni<4;++ni)
      bfr[ni] = *reinterpret_cast<const bf16x8*>(&vt[((size_t)kv*128 + wc+ni*16+lr)*2048 + c*64 + kf2*32 + lg*8]);
    #pragma unroll
    for (int mi=0;mi<4;++mi){
      #pragma unroll
      for (int ni=0;ni<4;++ni)
        acc[mi][ni] = MFMA16(af[mi], bfr[ni], acc[mi][ni]);
    }
  }
  #pragma unroll
  for (int mi=0;mi<4;++mi){
    #pragma unroll
    for (int ni=0;ni<4;++ni){
      #pragma unroll
      for (int r=0;r<4;++r)
        ckv[(sb*128 + wr+mi*16+lg*4+r)*128 + wc+ni*16+lr] = acc[mi][ni][r];
    }
  }
}

// ---------------- state scan; next-chunk loads prefetched before barriers ----------------
__global__ __launch_bounds__(256) void k_scan(const float* __restrict__ ckv, const float* __restrict__ eC,
                                              __hip_bfloat16* __restrict__ Stp){
  __shared__ float lds[8*128];
  int kv = blockIdx.y, bx = blockIdx.x;
  int tid = threadIdx.x;
  int kloc = tid >> 5;
  int kd  = bx*8 + kloc;
  int vd  = (tid*4) & 127;
  int oc = tid >> 5, lr = (tid >> 1) & 15, jh = (tid & 1)*4;
  int f  = bx >> 2, lg = bx & 3;
  float s0=0.f,s1=0.f,s2=0.f,s3=0.f;
  size_t sb0 = (size_t)kv*32;
  float e = eC[sb0*128 + kd];
  float4 u = reinterpret_cast<const float4*>(&ckv[(sb0*128 + kd)*128 + vd])[0];
  for (int c=0;c<32;++c){
    size_t sb = sb0 + c;
    float e_n = 0.f; float4 u_n = {0.f,0.f,0.f,0.f};
    if (c < 31){
      e_n = eC[(sb+1)*128 + kd];
      u_n = reinterpret_cast<const float4*>(&ckv[((sb+1)*128 + kd)*128 + vd])[0];
    }
    float4 cur = {s0,s1,s2,s3};
    *reinterpret_cast<float4*>(&lds[kloc*128 + vd]) = cur;
    __syncthreads();
    unsigned w0 = pk2(lds[(jh+0)*128 + oc*16+lr], lds[(jh+1)*128 + oc*16+lr]);
    unsigned w1 = pk2(lds[(jh+2)*128 + oc*16+lr], lds[(jh+3)*128 + oc*16+lr]);
    unsigned* dst = reinterpret_cast<unsigned*>(&Stp[((sb*8+oc)*4+f)*512 + (lg*16+lr)*8 + jh]);
    dst[0]=w0; dst[1]=w1;
    __syncthreads();
    s0 = (s0 + u.x)*e; s1 = (s1 + u.y)*e; s2 = (s2 + u.z)*e; s3 = (s3 + u.w)*e;
    e = e_n; u = u_n;
  }
}

// ---------------- causal flash attention, 4-way split-K ----------------
// Grid (64,16), block bx owns q-tile qt=63-bx (longest first; 4 blocks/CU
// resident backfills the tail). Q fragments reloaded per k-step (opaque-ptr
// defeats LICM) to keep VGPR < 128 -> 4 waves/SIMD.
__global__ __launch_bounds__(256) void k_attn(const __hip_bfloat16* __restrict__ qpk,
                                              const __hip_bfloat16* __restrict__ kpk,
                                              const __hip_bfloat16* __restrict__ vpk,
                                              float* __restrict__ ocomb){
  __shared__ __hip_bfloat16 OW[4][32][138];
  __shared__ float mW[4][32], lW[4][32];
  int h = blockIdx.y, kvh = h >> 2;
  int tid = threadIdx.x, w = tid >> 6, l = tid & 63;
  int ql = l & 31, kh = l >> 5;
  int qt = 63 - (int)blockIdx.x;
  int qbase = qt*32;
  int qg = qbase + ql;
  const __hip_bfloat16* qb = qpk + ((size_t)(h*64 + qt)*8)*512 + l*8;

  f32x16 zz = {0.f,0.f,0.f,0.f,0.f,0.f,0.f,0.f,0.f,0.f,0.f,0.f,0.f,0.f,0.f,0.f};
  f32x16 of[4];
  #pragma unroll
  for (int dt=0;dt<4;++dt) of[dt] = zz;
  float m = -1e30f, ll = 0.f;

  int nstep = qt/2 + 1;
  for (int s=w; s<nstep; s+=4){
    int kb = s*64;
    bool last = (s == nstep-1);
    f32x16 s0 = zz, s1 = zz;
    const __hip_bfloat16* qv = qb;
    #pragma unroll
    for (int i=0;i<8;++i){
      asm volatile("" : "+v"(qv));   // opaque: forces per-step Q reload (VGPR < 128)
      bf16x8 qf = *reinterpret_cast<const bf16x8*>(qv + (size_t)i*512);
      bf16x8 k0 = *reinterpret_cast<const bf16x8*>(&kpk[((size_t)(kvh*64 + 2*s)*8 + i)*512 + l*8]);
      s0 = MFMA32(k0, qf, s0);
      bf16x8 k1 = *reinterpret_cast<const bf16x8*>(&kpk[((size_t)(kvh*64 + 2*s+1)*8 + i)*512 + l*8]);
      s1 = MFMA32(k1, qf, s1);
    }
    if (last){
      #pragma unroll
      for (int r=0;r<16;++r){
        int kr = (r&3) + 8*(r>>2) + 4*kh;
        if (kb + kr > qg)      s0[r] = -1e30f;
        if (kb + 32 + kr > qg) s1[r] = -1e30f;
      }
    }
    float pmax = fmaxf(s0[0], s1[0]);
    #pragma unroll
    for (int r=1;r<16;++r) pmax = fmaxf(pmax, fmaxf(s0[r], s1[r]));
    pmax = fmaxf(pmax, __shfl_xor(pmax, 32));
    if (!__all(pmax <= m + 11.54f)){   // 8 nats in log2 units
      float nm = fmaxf(m, pmax);
      float ef = exp2f(m - nm);
      ll *= ef;
      #pragma unroll
      for (int dt=0;dt<4;++dt){
        #pragma unroll
        for (int r=0;r<16;++r) of[dt][r] *= ef;
      }
      m = nm;
    }
    float ps = 0.f;
    #pragma unroll
    for (int r=0;r<16;++r){ s0[r] = exp2f(s0[r]-m); ps += s0[r]; }
    #pragma unroll
    for (int r=0;r<16;++r){ s1[r] = exp2f(s1[r]-m); ps += s1[r]; }
    ps += __shfl_xor(ps, 32);
    ll += ps;
    unsigned pw[4][4];
    {
      unsigned a,b;
      a = pk2(s0[0],s0[1]);   b = pk2(s0[4],s0[5]);   pl32swap(a,b); pw[0][0]=a; pw[0][2]=b;
      a = pk2(s0[2],s0[3]);   b = pk2(s0[6],s0[7]);   pl32swap(a,b); pw[0][1]=a; pw[0][3]=b;
      a = pk2(s0[8],s0[9]);   b = pk2(s0[12],s0[13]); pl32swap(a,b); pw[1][0]=a; pw[1][2]=b;
      a = pk2(s0[10],s0[11]); b = pk2(s0[14],s0[15]); pl32swap(a,b); pw[1][1]=a; pw[1][3]=b;
      a = pk2(s1[0],s1[1]);   b = pk2(s1[4],s1[5]);   pl32swap(a,b); pw[2][0]=a; pw[2][2]=b;
      a = pk2(s1[2],s1[3]);   b = pk2(s1[6],s1[7]);   pl32swap(a,b); pw[2][1]=a; pw[2][3]=b;
      a = pk2(s1[8],s1[9]);   b = pk2(s1[12],s1[13]); pl32swap(a,b); pw[3][0]=a; pw[3][2]=b;
      a = pk2(s1[10],s1[11]); b = pk2(s1[14],s1[15]); pl32swap(a,b); pw[3][1]=a; pw[3][3]=b;
    }
    #pragma unroll
    for (int dt=0; dt<4; ++dt){
      #pragma unroll
      for (int kq=0; kq<4; ++kq){
        bf16x8 vf = *reinterpret_cast<const bf16x8*>(&vpk[((((size_t)kvh*32 + s)*4 + dt)*4 + kq)*512 + l*8]);
        u32x4 pu = {pw[kq][0], pw[kq][1], pw[kq][2], pw[kq][3]};
        bf16x8 pb = __builtin_bit_cast(bf16x8, pu);
        of[dt] = MFMA32(vf, pb, of[dt]);
      }
    }
  }
  // write partials to LDS
  if (kh == 0){ mW[w][ql] = m; lW[w][ql] = ll; }
  #pragma unroll
  for (int dt=0; dt<4; ++dt){
    #pragma unroll
    for (int rp=0; rp<4; ++rp){
      unsigned lo = pk2(of[dt][rp*4+0], of[dt][rp*4+1]);
      unsigned hi = pk2(of[dt][rp*4+2], of[dt][rp*4+3]);
      unsigned* dst = reinterpret_cast<unsigned*>(&OW[w][ql][dt*32 + 8*rp + 4*kh]);
      dst[0] = lo; dst[1] = hi;
    }
  }
  __syncthreads();
  // merge: thread handles q = tid>>3, d-range db..db+15
  int q = tid >> 3, db = (tid & 7)*16;
  float m0=mW[0][q], m1=mW[1][q], m2=mW[2][q], m3=mW[3][q];
  float ms = fmaxf(fmaxf(m0,m1), fmaxf(m2,m3));
  float fac[4] = {exp2f(m0-ms), exp2f(m1-ms), exp2f(m2-ms), exp2f(m3-ms)};
  float lt = fac[0]*lW[0][q] + fac[1]*lW[1][q] + fac[2]*lW[2][q] + fac[3]*lW[3][q];
  float acc[16];
  #pragma unroll
  for (int j=0;j<16;++j) acc[j] = 0.f;
  #pragma unroll
  for (int wv=0; wv<4; ++wv){
    const unsigned* src = reinterpret_cast<const unsigned*>(&OW[wv][q][db]);
    float fx = fac[wv];
    #pragma unroll
    for (int j=0;j<8;++j){
      unsigned u = src[j];
      acc[2*j]   += fx * __builtin_bit_cast(float, u << 16);
      acc[2*j+1] += fx * __builtin_bit_cast(float, u & 0xffff0000u);
    }
  }
  float inv = 0.5f / lt;
  float4 o0 = {acc[0]*inv, acc[1]*inv, acc[2]*inv, acc[3]*inv};
  float4 o1 = {acc[4]*inv, acc[5]*inv, acc[6]*inv, acc[7]*inv};
  float4 o2 = {acc[8]*inv, acc[9]*inv, acc[10]*inv, acc[11]*inv};
  float4 o3 = {acc[12]*inv, acc[13]*inv, acc[14]*inv, acc[15]*inv};
  float4* dst = reinterpret_cast<float4*>(&ocomb[(size_t)(qbase+q)*2048 + h*128 + db]);
  dst[0]=o0; dst[1]=o1; dst[2]=o2; dst[3]=o3;
}

// ---------------- GLA output: all operands fragment-packed, no barriers ----------------
__global__ __launch_bounds__(256) void k_gla_out(const __hip_bfloat16* __restrict__ qep,
                                                 const __hip_bfloat16* __restrict__ kep,
                                                 const __hip_bfloat16* __restrict__ vpk16,
                                                 const __hip_bfloat16* __restrict__ Stp,
                                                 const float* __restrict__ ocomb,
                                                 __hip_bfloat16* __restrict__ obf){
  __shared__ __hip_bfloat16 ldsp[4*16*72];
  int c = blockIdx.x, h = blockIdx.y, kvh = h >> 2;
  int tid = threadIdx.x, w = tid>>6, l = tid&63, lr = l&15, lg = l>>4;
  int t0 = c*64, r0 = w*16;
  __hip_bfloat16* myp = &ldsp[w*16*72];
  bf16x8 qef[4];
  #pragma unroll
  for (int f=0; f<4; ++f)
    qef[f] = *reinterpret_cast<const bf16x8*>(&qep[(((size_t)h*128 + c*4 + w)*4 + f)*512 + l*8]);
  f32x4 z = {0.f,0.f,0.f,0.f};
  f32x4 of[8];
  #pragma unroll
  for (int oc=0;oc<8;++oc) of[oc]=z;
  __builtin_amdgcn_s_setprio(1);
  // inter: qe @ S_{c-1}
  #pragma unroll
  for (int oc=0; oc<8; ++oc){
    #pragma unroll
    for (int f=0; f<4; ++f){
      bf16x8 sfr = *reinterpret_cast<const bf16x8*>(&Stp[((((size_t)kvh*32 + c)*8 + oc)*4 + f)*512 + l*8]);
      of[oc] = MFMA16(qef[f], sfr, of[oc]);
    }
  }
  // intra scores qe @ ke^T
  f32x4 sacc[4] = {z,z,z,z};
  #pragma unroll
  for (int cb=0; cb<4; ++cb){
    #pragma unroll
    for (int f=0; f<4; ++f){
      bf16x8 kf = *reinterpret_cast<const bf16x8*>(&kep[(((size_t)kvh*128 + c*4 + cb)*4 + f)*512 + l*8]);
      sacc[cb] = MFMA16(qef[f], kf, sacc[cb]);
    }
  }
  __builtin_amdgcn_s_setprio(0);
  #pragma unroll
  for (int cb=0; cb<4; ++cb){
    #pragma unroll
    for (int r=0;r<4;++r){
      int s_ = cb*16 + lr;
      int t_ = r0 + lg*4 + r;
      float v = (s_ <= t_) ? sacc[cb][r] : 0.f;
      myp[(lg*4 + r)*72 + cb*16 + lr] = f2bf(v);
    }
  }
  bf16x8 pf[2];
  #pragma unroll
  for (int kf2=0;kf2<2;++kf2)
    pf[kf2] = *reinterpret_cast<const bf16x8*>(&myp[lr*72 + kf2*32 + lg*8]);
  __builtin_amdgcn_s_setprio(1);
  #pragma unroll
  for (int oc=0; oc<8; ++oc){
    #pragma unroll
    for (int kf2=0;kf2<2;++kf2){
      bf16x8 vf = *reinterpret_cast<const bf16x8*>(&vpk16[((((size_t)kvh*32 + c)*8 + oc)*2 + kf2)*512 + l*8]);
      of[oc] = MFMA16(pf[kf2], vf, of[oc]);
    }
  }
  __builtin_amdgcn_s_setprio(0);
  #pragma unroll
  for (int oc=0;oc<8;++oc){
    #pragma unroll
    for (int r=0;r<4;++r){
      int row = t0 + r0 + lg*4 + r;
      int col = h*128 + oc*16 + lr;
      float prev = ocomb[(size_t)row*2048 + col];
      obf[(size_t)row*2048 + col] = f2bf(prev + 0.5f*of[oc][r]);
    }
  }
}

extern "C" void kernel_launch(void* const* d_in, const int* in_sizes, int n_in,
                              void* d_out, int out_size, void* d_ws, size_t ws_size,
                              hipStream_t stream) {
  const float* hs = (const float*)d_in[0];
  const float* Wq = (const float*)d_in[1];
  const float* Wk = (const float*)d_in[2];
  const float* Wv = (const float*)d_in[3];
  const float* Wo = (const float*)d_in[4];
  float* out = (float*)d_out;

  char* base = (char*)d_ws;
  size_t off = 0;
  auto alloc = [&](size_t bytes) -> void* {
    void* p = base + off;
    off = (off + bytes + 255) & ~(size_t)255;
    return p;
  };

  float*          ropeC  = (float*)alloc(2048*64*4);
  float*          ropeS  = (float*)alloc(2048*64*4);
  __hip_bfloat16* hsb    = (__hip_bfloat16*)alloc((size_t)4194304*2);
  __hip_bfloat16* WqkvT  = (__hip_bfloat16*)alloc((size_t)3072*2048*2);
  __hip_bfloat16* WoT    = (__hip_bfloat16*)alloc((size_t)4194304*2);
  float*          qkv    = (float*)alloc((size_t)2048*3072*4);
  __hip_bfloat16* qpk    = (__hip_bfloat16*)alloc((size_t)4194304*2);
  __hip_bfloat16* kpk    = (__hip_bfloat16*)alloc((size_t)1048576*2);
  __hip_bfloat16* vt     = (__hip_bfloat16*)alloc((size_t)1048576*2);
  __hip_bfloat16* vpk    = (__hip_bfloat16*)alloc((size_t)1048576*2);
  __hip_bfloat16* vpk16  = (__hip_bfloat16*)alloc((size_t)1048576*2);
  __hip_bfloat16* qep    = (__hip_bfloat16*)alloc((size_t)4194304*2);
  __hip_bfloat16* ke     = (__hip_bfloat16*)alloc((size_t)1048576*2);
  __hip_bfloat16* kep    = (__hip_bfloat16*)alloc((size_t)1048576*2);
  float*          bt_all = (float*)alloc((size_t)1048576*4);
  float*          eC     = (float*)alloc((size_t)4*32*128*4);
  float*          ckv    = (float*)alloc((size_t)4*32*128*128*4);
  __hip_bfloat16* Stp    = (__hip_bfloat16*)alloc((size_t)4*32*128*128*2);
  // aliases (lifetimes don't overlap):
  float*          ocomb  = qkv;                    // qkv f32 dead after postproc readers
  __hip_bfloat16* obf    = hsb;                    // hsb dead after qkv GEMM

  if (off > ws_size) return;

  k_rope_table<<<512, 256, 0, stream>>>(ropeC, ropeS);
  k_cvt_bf16<<<4096, 256, 0, stream>>>(hs, hsb, 1048576);
  k_transpose_w<<<dim3(2560), 256, 0, stream>>>(Wq, Wk, Wv, Wo, WqkvT, WoT);

  // fused QKV GEMM: [2048 x 3072] = hsb @ WqkvT^T ; 768 blocks = 3/CU
  k_gemm_lds2<<<dim3(768), 128, 0, stream>>>(hsb, WqkvT, qkv, 2048, 3072, 2048);

  k_gates<<<dim3(32,4), 128, 0, stream>>>(qkv, bt_all, eC);
  k_qkpost<<<dim3(10240), 256, 0, stream>>>(qkv, ropeC, ropeS, bt_all, qpk, qep, kpk, ke, kep);
  k_vprep<<<dim3(32,4), 256, 0, stream>>>(qkv, vt, vpk, vpk16);

  k_ckv<<<dim3(32,4), 256, 0, stream>>>(ke, vt, ckv);
  k_scan<<<dim3(16,4), 256, 0, stream>>>(ckv, eC, Stp);

  k_attn<<<dim3(64,16), 256, 0, stream>>>(qpk, kpk, vpk, ocomb);
  k_gla_out<<<dim3(32,16), 256, 0, stream>>>(qep, kep, vpk16, Stp, ocomb, obf);

  // out GEMM: 512 blocks = 2/CU
  k_gemm_lds2<<<dim3(512), 128, 0, stream>>>(obf, WoT, out, 2048, 2048, 2048);
}

// Round 14
// 267.977 us; speedup vs baseline: 1.0498x; 1.0498x over previous
//
#include <hip/hip_runtime.h>
#include <hip/hip_bf16.h>

typedef __bf16 bf16x8 __attribute__((ext_vector_type(8)));
typedef float f32x4 __attribute__((ext_vector_type(4)));
typedef float f32x16 __attribute__((ext_vector_type(16)));
typedef unsigned u32x4 __attribute__((ext_vector_type(4)));

#define MFMA16(a,b,c) __builtin_amdgcn_mfma_f32_16x16x32_bf16((a),(b),(c),0,0,0)
#define MFMA32(a,b,c) __builtin_amdgcn_mfma_f32_32x32x16_bf16((a),(b),(c),0,0,0)

__device__ __forceinline__ float bf2f(const __hip_bfloat16 h){ return __bfloat162float(h); }
__device__ __forceinline__ __hip_bfloat16 f2bf(float f){ return __float2bfloat16(f); }
__device__ __forceinline__ __bf16 f2raw(float f){
  return __builtin_bit_cast(__bf16, __builtin_bit_cast(unsigned short, __float2bfloat16(f)));
}

__device__ __forceinline__ unsigned pk2(float a, float b){
  unsigned lo = __builtin_bit_cast(unsigned short, __float2bfloat16(a));
  unsigned hi = __builtin_bit_cast(unsigned short, __float2bfloat16(b));
  return lo | (hi << 16);
}
__device__ __forceinline__ void pl32swap(unsigned &x, unsigned &y){
  asm volatile("v_permlane32_swap_b32 %0, %1" : "+v"(x), "+v"(y));
}
// async global->LDS, 16B per lane; lds dest = uniform base + lane*16
__device__ __forceinline__ void gload16(const void* g, void* l){
  __builtin_amdgcn_global_load_lds((const __attribute__((address_space(1))) unsigned int*)g,
                                   (__attribute__((address_space(3))) unsigned int*)l, 16, 0, 0);
}

// fragment-pack index for qpk/kpk (B-frag, 32-row tiles)
__device__ __forceinline__ size_t pk_idx(int grp, int ntile, int t, int d){
  int t32 = t >> 5, ql = t & 31, i = d >> 4, kh = (d >> 3) & 1, j = d & 7;
  return ((size_t)(grp*ntile + t32)*8 + i)*512 + (kh*32 + ql)*8 + j;
}
// fragment-pack index for qep/kep (16x16 B-frag, 16-row tiles)
__device__ __forceinline__ size_t ep_idx(int grp, int t, int d){
  int t16 = t >> 4, lr = t & 15, f = d >> 5, lg = (d >> 3) & 3, j = d & 7;
  return (((size_t)grp*128 + t16)*4 + f)*512 + (lg*16 + lr)*8 + j;
}

// ---------------- rope cos/sin table ----------------
__global__ void k_rope_table(float* __restrict__ ct, float* __restrict__ st){
  int e = blockIdx.x*256 + threadIdx.x;
  if (e >= 2048*64) return;
  int t = e >> 6, d = e & 63;
  float inv = expf(-(float)d * 0.14391156831212787f);
  float ang = (float)t * inv;
  ct[e] = cosf(ang);
  st[e] = sinf(ang);
}

// ---------------- f32 -> bf16 elementwise ----------------
__global__ void k_cvt_bf16(const float* __restrict__ in, __hip_bfloat16* __restrict__ out, int n4){
  int i = blockIdx.x*256 + threadIdx.x;
  if (i >= n4) return;
  float4 v = reinterpret_cast<const float4*>(in)[i];
  ushort4 o;
  o.x = __builtin_bit_cast(unsigned short, f2bf(v.x));
  o.y = __builtin_bit_cast(unsigned short, f2bf(v.y));
  o.z = __builtin_bit_cast(unsigned short, f2bf(v.z));
  o.w = __builtin_bit_cast(unsigned short, f2bf(v.w));
  reinterpret_cast<ushort4*>(out)[i] = o;
}

// ---------------- fused weight transposes: Wq,Wk,Wv -> WqkvT; Wo -> WoT ----------------
__global__ __launch_bounds__(256) void k_transpose_w(const float* __restrict__ Wq,
                                                     const float* __restrict__ Wk,
                                                     const float* __restrict__ Wv,
                                                     const float* __restrict__ Wo,
                                                     __hip_bfloat16* __restrict__ WqkvT,
                                                     __hip_bfloat16* __restrict__ WoT){
  __shared__ float tile[64][65];
  int id = blockIdx.x;
  const float* in; __hip_bfloat16* out; int C, bx, by;
  if (id < 1024)      { in=Wq; out=WqkvT;                         C=2048; bx=id&31;          by=id>>5; }
  else if (id < 1280) { int i=id-1024; in=Wk; out=WqkvT+(size_t)2048*2048; C=512; bx=i&7;    by=i>>3; }
  else if (id < 1536) { int i=id-1280; in=Wv; out=WqkvT+(size_t)2560*2048; C=512; bx=i&7;    by=i>>3; }
  else                { int i=id-1536; in=Wo; out=WoT;            C=2048; bx=i&31;           by=i>>5; }
  const int R = 2048;
  int ct_ = bx*64, rt = by*64;
  int tx = threadIdx.x & 63, ty = threadIdx.x >> 6;
  #pragma unroll
  for (int i=0;i<16;++i){ int lr = i*4 + ty; tile[lr][tx] = in[(size_t)(rt+lr)*C + ct_+tx]; }
  __syncthreads();
  #pragma unroll
  for (int i=0;i<16;++i){ int lr = i*4 + ty; out[(size_t)(ct_+lr)*R + rt+tx] = f2bf(tile[tx][lr]); }
}

// ---------------- GEMM: 128x64 tile, 2-wave blocks, XCD-swizzled 1D grid ----------------
__global__ __launch_bounds__(128) void k_gemm_lds2(const __hip_bfloat16* __restrict__ A,
                                                   const __hip_bfloat16* __restrict__ BT,
                                                   float* __restrict__ C, int M, int N, int K){
  __shared__ __hip_bfloat16 As[128*64];   // 16KB
  __shared__ __hip_bfloat16 Bs[64*64];    // 8KB
  int nwg = gridDim.x;
  int cpx = nwg >> 3;
  int wg  = blockIdx.x;
  int swz = (wg & 7)*cpx + (wg >> 3);     // bijective XCD swizzle
  int nbx = N >> 6;
  int bn = (swz % nbx)*64, bm = (swz / nbx)*128;
  int tid = threadIdx.x, w = tid >> 6, l = tid & 63, lr = l & 15, lg = l >> 4;
  int wr = w*64;
  int srow = tid >> 3;
  int scol = (tid & 7)*8;
  f32x4 z = {0.f,0.f,0.f,0.f};
  f32x4 acc[4][4];
  #pragma unroll
  for (int i=0;i<4;++i){
    #pragma unroll
    for (int j=0;j<4;++j) acc[i][j] = z;
  }
  for (int bk=0; bk<K; bk+=64){
    #pragma unroll
    for (int i=0;i<8;++i)
      gload16(&A[(size_t)(bm + i*16 + srow)*K + bk + scol], &As[i*1024 + tid*8]);
    #pragma unroll
    for (int i=0;i<4;++i)
      gload16(&BT[(size_t)(bn + i*16 + srow)*K + bk + scol], &Bs[i*1024 + tid*8]);
    __syncthreads();
    __builtin_amdgcn_s_setprio(1);
    #pragma unroll
    for (int kk=0; kk<2; ++kk){
      bf16x8 af[4], bfr[4];
      #pragma unroll
      for (int mi=0;mi<4;++mi) af[mi]  = *reinterpret_cast<const bf16x8*>(&As[(wr+mi*16+lr)*64 + kk*32 + lg*8]);
      #pragma unroll
      for (int ni=0;ni<4;++ni) bfr[ni] = *reinterpret_cast<const bf16x8*>(&Bs[(ni*16+lr)*64 + kk*32 + lg*8]);
      #pragma unroll
      for (int mi=0;mi<4;++mi){
        #pragma unroll
        for (int ni=0;ni<4;++ni)
          acc[mi][ni] = MFMA16(af[mi], bfr[ni], acc[mi][ni]);
      }
    }
    __builtin_amdgcn_s_setprio(0);
    __syncthreads();
  }
  #pragma unroll
  for (int mi=0;mi<4;++mi){
    #pragma unroll
    for (int ni=0;ni<4;++ni){
      #pragma unroll
      for (int r=0;r<4;++r)
        C[(size_t)(bm+wr+mi*16+lg*4+r)*N + (bn+ni*16+lr)] = acc[mi][ni][r];
    }
  }
}

// ---------------- gate cumsum (log2 domain): bt_all[t][kv][k], eC = 2^bC ----------------
__global__ __launch_bounds__(128) void k_gates(const float* __restrict__ qkv,
                                               float* __restrict__ bt_all,
                                               float* __restrict__ eC){
  int c = blockIdx.x, kv = blockIdx.y, k = threadIdx.x;
  float b = 0.f;
  #pragma unroll 8
  for (int t=0;t<64;++t){
    float x = qkv[(size_t)(c*64+t)*3072 + 2048 + kv*128 + k];
    float gl = (fminf(x,0.f) - log1pf(expf(-fabsf(x)))) * 0.09016844005f; // logsigmoid/16 * log2e
    b += gl;
    bt_all[(size_t)(c*64+t)*512 + kv*128 + k] = b;
  }
  eC[((size_t)kv*32 + c)*128 + k] = exp2f(b);
}

// ---------------- fused q+k postproc: softmax + rope + gate-scale ----------------
__global__ __launch_bounds__(256) void k_qkpost(const float* __restrict__ qkv, const float* __restrict__ ct,
                                                const float* __restrict__ st, const float* __restrict__ bt_all,
                                                __hip_bfloat16* __restrict__ qpk, __hip_bfloat16* __restrict__ qep,
                                                __hip_bfloat16* __restrict__ kpk, __hip_bfloat16* __restrict__ ke,
                                                __hip_bfloat16* __restrict__ kep){
  int bid = blockIdx.x;
  int i = threadIdx.x & 63;
  if (bid < 8192){
    int g = bid*4 + (threadIdx.x >> 6);
    int t = g >> 4, h = g & 15;
    size_t base = (size_t)t*3072 + h*128;
    float a = qkv[base + i], b = qkv[base + 64 + i];
    float mx = fmaxf(a,b);
    #pragma unroll
    for (int off=1; off<64; off<<=1) mx = fmaxf(mx, __shfl_xor(mx, off));
    float ea = expf(a-mx), eb = expf(b-mx);
    float sm = ea+eb;
    #pragma unroll
    for (int off=1; off<64; off<<=1) sm += __shfl_xor(sm, off);
    float r = 1.0f/sm;
    const float* bp = &bt_all[(size_t)t*512 + (h>>2)*128];
    qep[ep_idx(h, t, i)]    = f2bf(exp2f(bp[i])    * (ea*r));
    qep[ep_idx(h, t, 64+i)] = f2bf(exp2f(bp[64+i]) * (eb*r));
    const float scale = 0.12751745f; // (1/sqrt(128)) * log2(e)
    float co = ct[t*64+i], si = st[t*64+i];
    qpk[pk_idx(h, 64, t, i)]    = f2bf((a*co - b*si)*scale);
    qpk[pk_idx(h, 64, t, 64+i)] = f2bf((b*co + a*si)*scale);
  } else {
    int g = (bid-8192)*4 + (threadIdx.x >> 6);
    int t = g >> 2, kv = g & 3;
    size_t base = (size_t)t*3072 + 2048 + kv*128;
    float a = qkv[base + i], b = qkv[base + 64 + i];
    float mx = fmaxf(a,b);
    #pragma unroll
    for (int off=1; off<64; off<<=1) mx = fmaxf(mx, __shfl_xor(mx, off));
    float ea = expf(a-mx), eb = expf(b-mx);
    float sm = ea+eb;
    #pragma unroll
    for (int off=1; off<64; off<<=1) sm += __shfl_xor(sm, off);
    float r = 1.0f/sm;
    const float* bp = &bt_all[(size_t)t*512 + kv*128];
    float kea = exp2f(-bp[i])    * (ea*r);
    float keb = exp2f(-bp[64+i]) * (eb*r);
    size_t ob = ((size_t)t*4 + kv)*128;
    ke[ob+i]    = f2bf(kea);
    ke[ob+64+i] = f2bf(keb);
    kep[ep_idx(kv, t, i)]    = f2bf(kea);
    kep[ep_idx(kv, t, 64+i)] = f2bf(keb);
    float co = ct[t*64+i], si = st[t*64+i];
    kpk[pk_idx(kv, 64, t, i)]    = f2bf(a*co - b*si);
    kpk[pk_idx(kv, 64, t, 64+i)] = f2bf(b*co + a*si);
  }
}

// ---------------- fused V prep: qkv -> vt + vpk + vpk16 (one LDS pass) ----------------
__global__ __launch_bounds__(256) void k_vprep(const float* __restrict__ qkv,
                                               __hip_bfloat16* __restrict__ vt,
                                               __hip_bfloat16* __restrict__ vpk,
                                               __hip_bfloat16* __restrict__ vpk16){
  __shared__ float lds[64*132];
  int s = blockIdx.x, kv = blockIdx.y;
  int tid = threadIdx.x;
  #pragma unroll
  for (int it=0; it<8; ++it){
    int i = it*256 + tid;          // 0..2047 float4s
    int t = i >> 5, dc = (i & 31)*4;
    float4 v = *reinterpret_cast<const float4*>(&qkv[(size_t)(s*64+t)*3072 + 2560 + kv*128 + dc]);
    *reinterpret_cast<float4*>(&lds[t*132 + dc]) = v;
  }
  __syncthreads();
  #pragma unroll
  for (int it=0; it<4; ++it){
    int i = it*256 + tid;          // 0..1023
    int d = i >> 3, tg = (i & 7)*8;
    bf16x8 o;
    #pragma unroll
    for (int j=0;j<8;++j) o[j] = f2raw(lds[(tg+j)*132 + d]);
    *reinterpret_cast<bf16x8*>(&vt[((size_t)kv*128 + d)*2048 + s*64 + tg]) = o;
  }
  #pragma unroll
  for (int it=0; it<4; ++it){
    int j2 = it*256 + tid;
    int dt = j2 >> 8, kq = (j2 >> 6) & 3, l = j2 & 63;
    int ts = kq*16 + (l>>5)*8, ds = dt*32 + (l&31);
    bf16x8 o;
    #pragma unroll
    for (int j=0;j<8;++j) o[j] = f2raw(lds[(ts+j)*132 + ds]);
    *reinterpret_cast<bf16x8*>(&vpk[((((size_t)kv*32 + s)*4 + dt)*4 + kq)*512 + l*8]) = o;
  }
  #pragma unroll
  for (int it=0; it<4; ++it){
    int j3 = it*256 + tid;
    int oc = j3 >> 7, f2 = (j3 >> 6) & 1, l = j3 & 63;
    int ts = f2*32 + (l>>4)*8, ds = oc*16 + (l&15);
    bf16x8 o;
    #pragma unroll
    for (int j=0;j<8;++j) o[j] = f2raw(lds[(ts+j)*132 + ds]);
    *reinterpret_cast<bf16x8*>(&vpk16[((((size_t)kv*32 + s)*8 + oc)*2 + f2)*512 + l*8]) = o;
  }
}

// ---------------- per-chunk KV: ckv[kd][vd] = ke^T(128x64) @ v(64x128) ----------------
__global__ __launch_bounds__(256) void k_ckv(const __hip_bfloat16* __restrict__ ke,
                                             const __hip_bfloat16* __restrict__ vt,
                                             float* __restrict__ ckv){
  __shared__ __hip_bfloat16 kt[128*72];
  int c = blockIdx.x, kv = blockIdx.y;
  int tid = threadIdx.x, w = tid>>6, l = tid&63, lr=l&15, lg=l>>4;
  int wr = (w>>1)*64, wc = (w&1)*64;
  #pragma unroll
  for (int r=0;r<4;++r){
    int idx = r*256 + tid;
    int t  = idx >> 4;
    int k0 = (idx & 15)*8;
    bf16x8 v = *reinterpret_cast<const bf16x8*>(&ke[((size_t)(c*64+t)*4 + kv)*128 + k0]);
    #pragma unroll
    for (int j=0;j<8;++j) kt[(k0+j)*72 + t] = __builtin_bit_cast(__hip_bfloat16, (unsigned short)__builtin_bit_cast(unsigned short, v[j]));
  }
  __syncthreads();
  f32x4 z = {0.f,0.f,0.f,0.f};
  f32x4 acc[4][4];
  #pragma unroll
  for (int i=0;i<4;++i){
    #pragma unroll
    for (int j=0;j<4;++j) acc[i][j]=z;
  }
  size_t sb = (size_t)kv*32 + c;
  #pragma unroll
  for (int kf2=0;kf2<2;++kf2){
    bf16x8 af[4], bfr[4];
    #pragma unroll
    for (int mi=0;mi<4;++mi)
      af[mi] = *reinterpret_cast<const bf16x8*>(&kt[(wr+mi*16+lr)*72 + kf2*32 + lg*8]);
    #pragma unroll
    for (int ni=0;ni<4;++ni)
      bfr[ni] = *reinterpret_cast<const bf16x8*>(&vt[((size_t)kv*128 + wc+ni*16+lr)*2048 + c*64 + kf2*32 + lg*8]);
    #pragma unroll
    for (int mi=0;mi<4;++mi){
      #pragma unroll
      for (int ni=0;ni<4;++ni)
        acc[mi][ni] = MFMA16(af[mi], bfr[ni], acc[mi][ni]);
    }
  }
  #pragma unroll
  for (int mi=0;mi<4;++mi){
    #pragma unroll
    for (int ni=0;ni<4;++ni){
      #pragma unroll
      for (int r=0;r<4;++r)
        ckv[(sb*128 + wr+mi*16+lg*4+r)*128 + wc+ni*16+lr] = acc[mi][ni][r];
    }
  }
}

// ---------------- state scan; next-chunk loads prefetched before barriers ----------------
__global__ __launch_bounds__(256) void k_scan(const float* __restrict__ ckv, const float* __restrict__ eC,
                                              __hip_bfloat16* __restrict__ Stp){
  __shared__ float lds[8*128];
  int kv = blockIdx.y, bx = blockIdx.x;
  int tid = threadIdx.x;
  int kloc = tid >> 5;
  int kd  = bx*8 + kloc;
  int vd  = (tid*4) & 127;
  int oc = tid >> 5, lr = (tid >> 1) & 15, jh = (tid & 1)*4;
  int f  = bx >> 2, lg = bx & 3;
  float s0=0.f,s1=0.f,s2=0.f,s3=0.f;
  size_t sb0 = (size_t)kv*32;
  float e = eC[sb0*128 + kd];
  float4 u = reinterpret_cast<const float4*>(&ckv[(sb0*128 + kd)*128 + vd])[0];
  for (int c=0;c<32;++c){
    size_t sb = sb0 + c;
    float e_n = 0.f; float4 u_n = {0.f,0.f,0.f,0.f};
    if (c < 31){
      e_n = eC[(sb+1)*128 + kd];
      u_n = reinterpret_cast<const float4*>(&ckv[((sb+1)*128 + kd)*128 + vd])[0];
    }
    float4 cur = {s0,s1,s2,s3};
    *reinterpret_cast<float4*>(&lds[kloc*128 + vd]) = cur;
    __syncthreads();
    unsigned w0 = pk2(lds[(jh+0)*128 + oc*16+lr], lds[(jh+1)*128 + oc*16+lr]);
    unsigned w1 = pk2(lds[(jh+2)*128 + oc*16+lr], lds[(jh+3)*128 + oc*16+lr]);
    unsigned* dst = reinterpret_cast<unsigned*>(&Stp[((sb*8+oc)*4+f)*512 + (lg*16+lr)*8 + jh]);
    dst[0]=w0; dst[1]=w1;
    __syncthreads();
    s0 = (s0 + u.x)*e; s1 = (s1 + u.y)*e; s2 = (s2 + u.z)*e; s3 = (s3 + u.w)*e;
    e = e_n; u = u_n;
  }
}

// ---------------- causal flash attention, 4-way split-K, paired q-tiles (R11 version) ----------------
__global__ __launch_bounds__(256) void k_attn(const __hip_bfloat16* __restrict__ qpk,
                                              const __hip_bfloat16* __restrict__ kpk,
                                              const __hip_bfloat16* __restrict__ vpk,
                                              float* __restrict__ ocomb){
  __shared__ __hip_bfloat16 OW[4][32][138];
  __shared__ float mW[4][32], lW[4][32];
  int h = blockIdx.y, kvh = h >> 2;
  int tid = threadIdx.x, w = tid >> 6, l = tid & 63;
  int ql = l & 31, kh = l >> 5;

  #pragma unroll 1
  for (int half=0; half<2; ++half){
    int qt = half ? (63 - (int)blockIdx.x) : (int)blockIdx.x;
    int qbase = qt*32;
    int qg = qbase + ql;

    bf16x8 qf[8];
    #pragma unroll
    for (int i=0;i<8;++i)
      qf[i] = *reinterpret_cast<const bf16x8*>(&qpk[((size_t)(h*64 + qt)*8 + i)*512 + l*8]);

    f32x16 zz = {0.f,0.f,0.f,0.f,0.f,0.f,0.f,0.f,0.f,0.f,0.f,0.f,0.f,0.f,0.f,0.f};
    f32x16 of[4];
    #pragma unroll
    for (int dt=0;dt<4;++dt) of[dt] = zz;
    float m = -1e30f, ll = 0.f;

    int nstep = qt/2 + 1;
    for (int s=w; s<nstep; s+=4){
      int kb = s*64;
      bool last = (s == nstep-1);
      f32x16 s0 = zz, s1 = zz;
      #pragma unroll
      for (int i=0;i<8;++i){
        bf16x8 k0 = *reinterpret_cast<const bf16x8*>(&kpk[((size_t)(kvh*64 + 2*s)*8 + i)*512 + l*8]);
        s0 = MFMA32(k0, qf[i], s0);
      }
      #pragma unroll
      for (int i=0;i<8;++i){
        bf16x8 k1 = *reinterpret_cast<const bf16x8*>(&kpk[((size_t)(kvh*64 + 2*s+1)*8 + i)*512 + l*8]);
        s1 = MFMA32(k1, qf[i], s1);
      }
      if (last){
        #pragma unroll
        for (int r=0;r<16;++r){
          int kr = (r&3) + 8*(r>>2) + 4*kh;
          if (kb + kr > qg)      s0[r] = -1e30f;
          if (kb + 32 + kr > qg) s1[r] = -1e30f;
        }
      }
      float pmax = fmaxf(s0[0], s1[0]);
      #pragma unroll
      for (int r=1;r<16;++r) pmax = fmaxf(pmax, fmaxf(s0[r], s1[r]));
      pmax = fmaxf(pmax, __shfl_xor(pmax, 32));
      if (!__all(pmax <= m + 11.54f)){   // 8 nats in log2 units
        float nm = fmaxf(m, pmax);
        float ef = exp2f(m - nm);
        ll *= ef;
        #pragma unroll
        for (int dt=0;dt<4;++dt){
          #pragma unroll
          for (int r=0;r<16;++r) of[dt][r] *= ef;
        }
        m = nm;
      }
      float ps = 0.f;
      #pragma unroll
      for (int r=0;r<16;++r){ s0[r] = exp2f(s0[r]-m); ps += s0[r]; }
      #pragma unroll
      for (int r=0;r<16;++r){ s1[r] = exp2f(s1[r]-m); ps += s1[r]; }
      ps += __shfl_xor(ps, 32);
      ll += ps;
      unsigned pw[4][4];
      {
        unsigned a,b;
        a = pk2(s0[0],s0[1]);   b = pk2(s0[4],s0[5]);   pl32swap(a,b); pw[0][0]=a; pw[0][2]=b;
        a = pk2(s0[2],s0[3]);   b = pk2(s0[6],s0[7]);   pl32swap(a,b); pw[0][1]=a; pw[0][3]=b;
        a = pk2(s0[8],s0[9]);   b = pk2(s0[12],s0[13]); pl32swap(a,b); pw[1][0]=a; pw[1][2]=b;
        a = pk2(s0[10],s0[11]); b = pk2(s0[14],s0[15]); pl32swap(a,b); pw[1][1]=a; pw[1][3]=b;
        a = pk2(s1[0],s1[1]);   b = pk2(s1[4],s1[5]);   pl32swap(a,b); pw[2][0]=a; pw[2][2]=b;
        a = pk2(s1[2],s1[3]);   b = pk2(s1[6],s1[7]);   pl32swap(a,b); pw[2][1]=a; pw[2][3]=b;
        a = pk2(s1[8],s1[9]);   b = pk2(s1[12],s1[13]); pl32swap(a,b); pw[3][0]=a; pw[3][2]=b;
        a = pk2(s1[10],s1[11]); b = pk2(s1[14],s1[15]); pl32swap(a,b); pw[3][1]=a; pw[3][3]=b;
      }
      #pragma unroll
      for (int dt=0; dt<4; ++dt){
        #pragma unroll
        for (int kq=0; kq<4; ++kq){
          bf16x8 vf = *reinterpret_cast<const bf16x8*>(&vpk[((((size_t)kvh*32 + s)*4 + dt)*4 + kq)*512 + l*8]);
          u32x4 pu = {pw[kq][0], pw[kq][1], pw[kq][2], pw[kq][3]};
          bf16x8 pb = __builtin_bit_cast(bf16x8, pu);
          of[dt] = MFMA32(vf, pb, of[dt]);
        }
      }
    }
    // write partials to LDS
    if (kh == 0){ mW[w][ql] = m; lW[w][ql] = ll; }
    #pragma unroll
    for (int dt=0; dt<4; ++dt){
      #pragma unroll
      for (int rp=0; rp<4; ++rp){
        unsigned lo = pk2(of[dt][rp*4+0], of[dt][rp*4+1]);
        unsigned hi = pk2(of[dt][rp*4+2], of[dt][rp*4+3]);
        unsigned* dst = reinterpret_cast<unsigned*>(&OW[w][ql][dt*32 + 8*rp + 4*kh]);
        dst[0] = lo; dst[1] = hi;
      }
    }
    __syncthreads();
    // merge: thread handles q = tid>>3, d-range db..db+15
    int q = tid >> 3, db = (tid & 7)*16;
    float m0=mW[0][q], m1=mW[1][q], m2=mW[2][q], m3=mW[3][q];
    float ms = fmaxf(fmaxf(m0,m1), fmaxf(m2,m3));
    float fac[4] = {exp2f(m0-ms), exp2f(m1-ms), exp2f(m2-ms), exp2f(m3-ms)};
    float lt = fac[0]*lW[0][q] + fac[1]*lW[1][q] + fac[2]*lW[2][q] + fac[3]*lW[3][q];
    float acc[16];
    #pragma unroll
    for (int j=0;j<16;++j) acc[j] = 0.f;
    #pragma unroll
    for (int wv=0; wv<4; ++wv){
      const unsigned* src = reinterpret_cast<const unsigned*>(&OW[wv][q][db]);
      float fx = fac[wv];
      #pragma unroll
      for (int j=0;j<8;++j){
        unsigned u = src[j];
        acc[2*j]   += fx * __builtin_bit_cast(float, u << 16);
        acc[2*j+1] += fx * __builtin_bit_cast(float, u & 0xffff0000u);
      }
    }
    float inv = 0.5f / lt;
    float4 o0 = {acc[0]*inv, acc[1]*inv, acc[2]*inv, acc[3]*inv};
    float4 o1 = {acc[4]*inv, acc[5]*inv, acc[6]*inv, acc[7]*inv};
    float4 o2 = {acc[8]*inv, acc[9]*inv, acc[10]*inv, acc[11]*inv};
    float4 o3 = {acc[12]*inv, acc[13]*inv, acc[14]*inv, acc[15]*inv};
    float4* dst = reinterpret_cast<float4*>(&ocomb[(size_t)(qbase+q)*2048 + h*128 + db]);
    dst[0]=o0; dst[1]=o1; dst[2]=o2; dst[3]=o3;
    __syncthreads();   // LDS reused by next half
  }
}

// ---------------- GLA output: all operands fragment-packed, no barriers ----------------
__global__ __launch_bounds__(256) void k_gla_out(const __hip_bfloat16* __restrict__ qep,
                                                 const __hip_bfloat16* __restrict__ kep,
                                                 const __hip_bfloat16* __restrict__ vpk16,
                                                 const __hip_bfloat16* __restrict__ Stp,
                                                 const float* __restrict__ ocomb,
                                                 __hip_bfloat16* __restrict__ obf){
  __shared__ __hip_bfloat16 ldsp[4*16*72];
  int c = blockIdx.x, h = blockIdx.y, kvh = h >> 2;
  int tid = threadIdx.x, w = tid>>6, l = tid&63, lr = l&15, lg = l>>4;
  int t0 = c*64, r0 = w*16;
  __hip_bfloat16* myp = &ldsp[w*16*72];
  bf16x8 qef[4];
  #pragma unroll
  for (int f=0; f<4; ++f)
    qef[f] = *reinterpret_cast<const bf16x8*>(&qep[(((size_t)h*128 + c*4 + w)*4 + f)*512 + l*8]);
  f32x4 z = {0.f,0.f,0.f,0.f};
  f32x4 of[8];
  #pragma unroll
  for (int oc=0;oc<8;++oc) of[oc]=z;
  __builtin_amdgcn_s_setprio(1);
  // inter: qe @ S_{c-1}
  #pragma unroll
  for (int oc=0; oc<8; ++oc){
    #pragma unroll
    for (int f=0; f<4; ++f){
      bf16x8 sfr = *reinterpret_cast<const bf16x8*>(&Stp[((((size_t)kvh*32 + c)*8 + oc)*4 + f)*512 + l*8]);
      of[oc] = MFMA16(qef[f], sfr, of[oc]);
    }
  }
  // intra scores qe @ ke^T
  f32x4 sacc[4] = {z,z,z,z};
  #pragma unroll
  for (int cb=0; cb<4; ++cb){
    #pragma unroll
    for (int f=0; f<4; ++f){
      bf16x8 kf = *reinterpret_cast<const bf16x8*>(&kep[(((size_t)kvh*128 + c*4 + cb)*4 + f)*512 + l*8]);
      sacc[cb] = MFMA16(qef[f], kf, sacc[cb]);
    }
  }
  __builtin_amdgcn_s_setprio(0);
  #pragma unroll
  for (int cb=0; cb<4; ++cb){
    #pragma unroll
    for (int r=0;r<4;++r){
      int s_ = cb*16 + lr;
      int t_ = r0 + lg*4 + r;
      float v = (s_ <= t_) ? sacc[cb][r] : 0.f;
      myp[(lg*4 + r)*72 + cb*16 + lr] = f2bf(v);
    }
  }
  bf16x8 pf[2];
  #pragma unroll
  for (int kf2=0;kf2<2;++kf2)
    pf[kf2] = *reinterpret_cast<const bf16x8*>(&myp[lr*72 + kf2*32 + lg*8]);
  __builtin_amdgcn_s_setprio(1);
  #pragma unroll
  for (int oc=0; oc<8; ++oc){
    #pragma unroll
    for (int kf2=0;kf2<2;++kf2){
      bf16x8 vf = *reinterpret_cast<const bf16x8*>(&vpk16[((((size_t)kvh*32 + c)*8 + oc)*2 + kf2)*512 + l*8]);
      of[oc] = MFMA16(pf[kf2], vf, of[oc]);
    }
  }
  __builtin_amdgcn_s_setprio(0);
  #pragma unroll
  for (int oc=0;oc<8;++oc){
    #pragma unroll
    for (int r=0;r<4;++r){
      int row = t0 + r0 + lg*4 + r;
      int col = h*128 + oc*16 + lr;
      float prev = ocomb[(size_t)row*2048 + col];
      obf[(size_t)row*2048 + col] = f2bf(prev + 0.5f*of[oc][r]);
    }
  }
}

extern "C" void kernel_launch(void* const* d_in, const int* in_sizes, int n_in,
                              void* d_out, int out_size, void* d_ws, size_t ws_size,
                              hipStream_t stream) {
  const float* hs = (const float*)d_in[0];
  const float* Wq = (const float*)d_in[1];
  const float* Wk = (const float*)d_in[2];
  const float* Wv = (const float*)d_in[3];
  const float* Wo = (const float*)d_in[4];
  float* out = (float*)d_out;

  char* base = (char*)d_ws;
  size_t off = 0;
  auto alloc = [&](size_t bytes) -> void* {
    void* p = base + off;
    off = (off + bytes + 255) & ~(size_t)255;
    return p;
  };

  float*          ropeC  = (float*)alloc(2048*64*4);
  float*          ropeS  = (float*)alloc(2048*64*4);
  __hip_bfloat16* hsb    = (__hip_bfloat16*)alloc((size_t)4194304*2);
  __hip_bfloat16* WqkvT  = (__hip_bfloat16*)alloc((size_t)3072*2048*2);
  __hip_bfloat16* WoT    = (__hip_bfloat16*)alloc((size_t)4194304*2);
  float*          qkv    = (float*)alloc((size_t)2048*3072*4);
  __hip_bfloat16* qpk    = (__hip_bfloat16*)alloc((size_t)4194304*2);
  __hip_bfloat16* kpk    = (__hip_bfloat16*)alloc((size_t)1048576*2);
  __hip_bfloat16* vt     = (__hip_bfloat16*)alloc((size_t)1048576*2);
  __hip_bfloat16* vpk    = (__hip_bfloat16*)alloc((size_t)1048576*2);
  __hip_bfloat16* vpk16  = (__hip_bfloat16*)alloc((size_t)1048576*2);
  __hip_bfloat16* qep    = (__hip_bfloat16*)alloc((size_t)4194304*2);
  __hip_bfloat16* ke     = (__hip_bfloat16*)alloc((size_t)1048576*2);
  __hip_bfloat16* kep    = (__hip_bfloat16*)alloc((size_t)1048576*2);
  float*          bt_all = (float*)alloc((size_t)1048576*4);
  float*          eC     = (float*)alloc((size_t)4*32*128*4);
  float*          ckv    = (float*)alloc((size_t)4*32*128*128*4);
  __hip_bfloat16* Stp    = (__hip_bfloat16*)alloc((size_t)4*32*128*128*2);
  // aliases (lifetimes don't overlap):
  float*          ocomb  = qkv;                    // qkv f32 dead after postproc readers
  __hip_bfloat16* obf    = hsb;                    // hsb dead after qkv GEMM

  if (off > ws_size) return;

  k_rope_table<<<512, 256, 0, stream>>>(ropeC, ropeS);
  k_cvt_bf16<<<4096, 256, 0, stream>>>(hs, hsb, 1048576);
  k_transpose_w<<<dim3(2560), 256, 0, stream>>>(Wq, Wk, Wv, Wo, WqkvT, WoT);

  // fused QKV GEMM: [2048 x 3072] = hsb @ WqkvT^T ; 768 blocks = 3/CU
  k_gemm_lds2<<<dim3(768), 128, 0, stream>>>(hsb, WqkvT, qkv, 2048, 3072, 2048);

  k_gates<<<dim3(32,4), 128, 0, stream>>>(qkv, bt_all, eC);
  k_qkpost<<<dim3(10240), 256, 0, stream>>>(qkv, ropeC, ropeS, bt_all, qpk, qep, kpk, ke, kep);
  k_vprep<<<dim3(32,4), 256, 0, stream>>>(qkv, vt, vpk, vpk16);

  k_ckv<<<dim3(32,4), 256, 0, stream>>>(ke, vt, ckv);
  k_scan<<<dim3(16,4), 256, 0, stream>>>(ckv, eC, Stp);

  k_attn<<<dim3(32,16), 256, 0, stream>>>(qpk, kpk, vpk, ocomb);
  k_gla_out<<<dim3(32,16), 256, 0, stream>>>(qep, kep, vpk16, Stp, ocomb, obf);

  // out GEMM: 512 blocks = 2/CU
  k_gemm_lds2<<<dim3(512), 128, 0, stream>>>(obf, WoT, out, 2048, 2048, 2048);
}